// Round 3
// baseline (1579.825 us; speedup 1.0000x reference)
//
#include <hip/hip_runtime.h>
#include <hip/hip_bf16.h>

#define N_CTX 4096
#define NH    16
#define DH    64
#define DIM   1024   // NH * DH

// ---------------------------------------------------------------------------
// prep: x (N, DIM) fp32 -> rope -> l2norm -> * qk_scale -> xp (H, N, D) fp32
// one wave (64 lanes) per (n, h) row; 4 waves per block
// ---------------------------------------------------------------------------
__global__ __launch_bounds__(256) void prep_kernel(
    const float* __restrict__ x, const float* __restrict__ qk_scale,
    float* __restrict__ xp)
{
    const int lane = threadIdx.x & 63;
    const int wave = threadIdx.x >> 6;
    const int row  = blockIdx.x * 4 + wave;   // row = n*NH + h
    const int n = row >> 4;
    const int h = row & 15;

    float val = x[(size_t)n * DIM + h * DH + lane];
    float other = __shfl_xor(val, 1, 64);

    // rope tables, fp32 exactly like the numpy reference
    const int i = lane >> 1;                          // freq index 0..31
    float inv_freq = 1.0f / powf(10000.0f, (float)i * (1.0f / 32.0f));
    float ang = (float)n * inv_freq;
    float s, c;
    sincosf(ang, &s, &c);

    // even lane: xr*c - xi*s ; odd lane: xr*s + xi*c  (xr=even elem, xi=odd)
    float r = (lane & 1) ? fmaf(other, s, val * c)
                         : fmaf(val, c, -(other * s));

    // l2 norm over the 64 head elements
    float ss = r * r;
    #pragma unroll
    for (int off = 32; off > 0; off >>= 1)
        ss += __shfl_xor(ss, off, 64);
    float norm = sqrtf(ss);
    float invn = 1.0f / fmaxf(norm, 1e-12f);
    float scl  = qk_scale[lane];

    xp[((size_t)h * N_CTX + n) * DH + lane] = r * invn * scl;
}

// ---------------------------------------------------------------------------
// attn: flash-style online softmax. one block = (head, 64-query tile).
// 256 threads, each owns a 4x4 register tile of S / O.
// ---------------------------------------------------------------------------
__global__ __launch_bounds__(256) void attn_kernel(
    const float* __restrict__ qp, const float* __restrict__ kp,
    const float* __restrict__ v, float* __restrict__ attn_out)
{
    __shared__ float Qs[64][68];
    __shared__ float Ks[64][68];
    __shared__ float Vs[64][68];
    __shared__ float Ps[64][68];   // P transposed: Ps[j][i]

    const int h     = blockIdx.y;
    const int qbase = blockIdx.x * 64;
    const int t  = threadIdx.x;
    const int tr = t >> 4;     // 0..15 -> query rows i0..i0+3
    const int tc = t & 15;     // 0..15 -> key cols j0..j0+3 (and O cols d0..d0+3)
    const int i0 = tr * 4;
    const int j0 = tc * 4;

    // load Q tile (coalesced)
    for (int e = t; e < 64 * 64; e += 256) {
        int r = e >> 6, cc = e & 63;
        Qs[r][cc] = qp[((size_t)h * N_CTX + qbase + r) * DH + cc];
    }

    float o[4][4];
    float m[4], l[4];
    #pragma unroll
    for (int a = 0; a < 4; a++) {
        m[a] = -1e30f; l[a] = 0.0f;
        #pragma unroll
        for (int b = 0; b < 4; b++) o[a][b] = 0.0f;
    }

    for (int kt = 0; kt < N_CTX / 64; kt++) {
        __syncthreads();   // prev compute done (also covers Q-tile load on kt=0)
        for (int e = t; e < 64 * 64; e += 256) {
            int r = e >> 6, cc = e & 63;
            Ks[r][cc] = kp[((size_t)h * N_CTX + kt * 64 + r) * DH + cc];
            Vs[r][cc] = v[(size_t)(kt * 64 + r) * DIM + h * DH + cc];
        }
        __syncthreads();

        // S = (Q K^T) * D^-0.5, 4x4 per thread
        float s[4][4];
        #pragma unroll
        for (int a = 0; a < 4; a++)
            #pragma unroll
            for (int b = 0; b < 4; b++) s[a][b] = 0.0f;

        for (int d = 0; d < 64; d += 4) {
            float4 qv[4], kv[4];
            #pragma unroll
            for (int a = 0; a < 4; a++) qv[a] = *(const float4*)&Qs[i0 + a][d];
            #pragma unroll
            for (int b = 0; b < 4; b++) kv[b] = *(const float4*)&Ks[j0 + b][d];
            #pragma unroll
            for (int a = 0; a < 4; a++)
                #pragma unroll
                for (int b = 0; b < 4; b++) {
                    s[a][b] = fmaf(qv[a].x, kv[b].x, s[a][b]);
                    s[a][b] = fmaf(qv[a].y, kv[b].y, s[a][b]);
                    s[a][b] = fmaf(qv[a].z, kv[b].z, s[a][b]);
                    s[a][b] = fmaf(qv[a].w, kv[b].w, s[a][b]);
                }
        }

        // online softmax per row (16 threads per row share via width-16 shuffles)
        #pragma unroll
        for (int a = 0; a < 4; a++) {
            #pragma unroll
            for (int b = 0; b < 4; b++) s[a][b] *= 0.125f;   // D^-0.5

            float mx = fmaxf(fmaxf(s[a][0], s[a][1]), fmaxf(s[a][2], s[a][3]));
            mx = fmaxf(mx, __shfl_xor(mx, 1, 16));
            mx = fmaxf(mx, __shfl_xor(mx, 2, 16));
            mx = fmaxf(mx, __shfl_xor(mx, 4, 16));
            mx = fmaxf(mx, __shfl_xor(mx, 8, 16));

            float mnew  = fmaxf(m[a], mx);
            float alpha = __expf(m[a] - mnew);

            float psum = 0.0f;
            #pragma unroll
            for (int b = 0; b < 4; b++) {
                s[a][b] = __expf(s[a][b] - mnew);
                psum += s[a][b];
            }
            psum += __shfl_xor(psum, 1, 16);
            psum += __shfl_xor(psum, 2, 16);
            psum += __shfl_xor(psum, 4, 16);
            psum += __shfl_xor(psum, 8, 16);

            l[a] = l[a] * alpha + psum;
            m[a] = mnew;
            #pragma unroll
            for (int b = 0; b < 4; b++) o[a][b] *= alpha;
        }

        // write P transposed for float4 PV reads
        #pragma unroll
        for (int b = 0; b < 4; b++) {
            float4 pv;
            pv.x = s[0][b]; pv.y = s[1][b]; pv.z = s[2][b]; pv.w = s[3][b];
            *(float4*)&Ps[j0 + b][i0] = pv;
        }
        __syncthreads();

        // O[i][d] += sum_j P[i][j] * V[j][d]
        for (int jj = 0; jj < 64; jj++) {
            float4 pv = *(const float4*)&Ps[jj][i0];
            float4 vv = *(const float4*)&Vs[jj][j0];
            float pa[4] = {pv.x, pv.y, pv.z, pv.w};
            float vb[4] = {vv.x, vv.y, vv.z, vv.w};
            #pragma unroll
            for (int a = 0; a < 4; a++)
                #pragma unroll
                for (int b = 0; b < 4; b++)
                    o[a][b] = fmaf(pa[a], vb[b], o[a][b]);
        }
    }

    // epilogue: divide by l, write (N, DIM) fp32
    #pragma unroll
    for (int a = 0; a < 4; a++) {
        float invl = 1.0f / l[a];
        float4 ov;
        ov.x = o[a][0] * invl; ov.y = o[a][1] * invl;
        ov.z = o[a][2] * invl; ov.w = o[a][3] * invl;
        *(float4*)&attn_out[((size_t)(qbase + i0 + a)) * DIM + h * DH + j0] = ov;
    }
}

// ---------------------------------------------------------------------------
// proj: out[n][o] = sum_c attn[n][c] * w[o][c] + b[o], fp32 out
// 64x64 output tile per block, 4x4 register tile per thread
// ---------------------------------------------------------------------------
__global__ __launch_bounds__(256) void proj_kernel(
    const float* __restrict__ attn, const float* __restrict__ w,
    const float* __restrict__ bias, float* __restrict__ out)
{
    __shared__ float As[64][68];
    __shared__ float Ws[64][68];

    const int nbase = blockIdx.x * 64;
    const int obase = blockIdx.y * 64;
    const int t  = threadIdx.x;
    const int tr = t >> 4;
    const int tc = t & 15;
    const int i0 = tr * 4;   // n rows
    const int j0 = tc * 4;   // o cols

    float acc[4][4];
    #pragma unroll
    for (int a = 0; a < 4; a++)
        #pragma unroll
        for (int b = 0; b < 4; b++) acc[a][b] = 0.0f;

    for (int ct = 0; ct < DIM / 64; ct++) {
        __syncthreads();
        for (int e = t; e < 64 * 64; e += 256) {
            int r = e >> 6, cc = e & 63;
            As[r][cc] = attn[(size_t)(nbase + r) * DIM + ct * 64 + cc];
            Ws[r][cc] = w[(size_t)(obase + r) * DIM + ct * 64 + cc];
        }
        __syncthreads();

        for (int d = 0; d < 64; d += 4) {
            float4 av[4], wv[4];
            #pragma unroll
            for (int a = 0; a < 4; a++) av[a] = *(const float4*)&As[i0 + a][d];
            #pragma unroll
            for (int b = 0; b < 4; b++) wv[b] = *(const float4*)&Ws[j0 + b][d];
            #pragma unroll
            for (int a = 0; a < 4; a++)
                #pragma unroll
                for (int b = 0; b < 4; b++) {
                    acc[a][b] = fmaf(av[a].x, wv[b].x, acc[a][b]);
                    acc[a][b] = fmaf(av[a].y, wv[b].y, acc[a][b]);
                    acc[a][b] = fmaf(av[a].z, wv[b].z, acc[a][b]);
                    acc[a][b] = fmaf(av[a].w, wv[b].w, acc[a][b]);
                }
        }
    }

    #pragma unroll
    for (int a = 0; a < 4; a++)
        #pragma unroll
        for (int b = 0; b < 4; b++) {
            float bb = bias[obase + j0 + b];
            out[(size_t)(nbase + i0 + a) * DIM + obase + j0 + b] = acc[a][b] + bb;
        }
}

// ---------------------------------------------------------------------------
extern "C" void kernel_launch(void* const* d_in, const int* in_sizes, int n_in,
                              void* d_out, int out_size, void* d_ws, size_t ws_size,
                              hipStream_t stream)
{
    const float* q        = (const float*)d_in[0];
    const float* k        = (const float*)d_in[1];
    const float* v        = (const float*)d_in[2];
    const float* qk_scale = (const float*)d_in[3];
    const float* w_out    = (const float*)d_in[4];
    const float* b_out    = (const float*)d_in[5];
    float* out = (float*)d_out;

    const size_t per = (size_t)NH * N_CTX * DH;   // 4.19M floats
    float* qp   = (float*)d_ws;
    float* kp   = qp + per;
    float* attn = kp + per;                        // (N, DIM) fp32

    prep_kernel<<<dim3(N_CTX * NH / 4), 256, 0, stream>>>(q, qk_scale, qp);
    prep_kernel<<<dim3(N_CTX * NH / 4), 256, 0, stream>>>(k, qk_scale, kp);
    attn_kernel<<<dim3(N_CTX / 64, NH), 256, 0, stream>>>(qp, kp, v, attn);
    proj_kernel<<<dim3(N_CTX / 64, DIM / 64), 256, 0, stream>>>(attn, w_out, b_out, out);
}

// Round 4
// 457.867 us; speedup vs baseline: 3.4504x; 3.4504x over previous
//
#include <hip/hip_runtime.h>
#include <hip/hip_bf16.h>

#define N_CTX 4096
#define NH    16
#define DH    64
#define DIM   1024   // NH * DH

typedef __attribute__((ext_vector_type(8))) short bf16x8;  // 8 bf16 in 4 VGPRs
typedef __attribute__((ext_vector_type(4))) float f32x4;   // MFMA C/D

// RNE float->bf16 (bit manipulation, deterministic)
__device__ __forceinline__ ushort f2bf(float f) {
    union { float f; unsigned u; } x; x.f = f;
    unsigned r = (x.u + 0x7FFFu + ((x.u >> 16) & 1u)) >> 16;
    return (ushort)r;
}

// ---------------------------------------------------------------------------
// prep: x (N, DIM) fp32 -> rope -> l2norm -> * qk_scale -> xb bf16 [h][n][d]
// one wave per (n, h) row; 4 waves per block
// ---------------------------------------------------------------------------
__global__ __launch_bounds__(256) void prep_kernel(
    const float* __restrict__ x, const float* __restrict__ qk_scale,
    ushort* __restrict__ xb)
{
    const int lane = threadIdx.x & 63;
    const int wave = threadIdx.x >> 6;
    const int row  = blockIdx.x * 4 + wave;   // row = n*NH + h
    const int n = row >> 4;
    const int h = row & 15;

    float val = x[(size_t)n * DIM + h * DH + lane];
    float other = __shfl_xor(val, 1, 64);

    const int i = lane >> 1;
    float inv_freq = 1.0f / powf(10000.0f, (float)i * (1.0f / 32.0f));
    float ang = (float)n * inv_freq;
    float s, c;
    sincosf(ang, &s, &c);

    float r = (lane & 1) ? fmaf(other, s, val * c)
                         : fmaf(val, c, -(other * s));

    float ss = r * r;
    #pragma unroll
    for (int off = 32; off > 0; off >>= 1)
        ss += __shfl_xor(ss, off, 64);
    float invn = 1.0f / fmaxf(sqrtf(ss), 1e-12f);
    float scl  = qk_scale[lane];

    xb[((size_t)h * N_CTX + n) * DH + lane] = f2bf(r * invn * scl);
}

// ---------------------------------------------------------------------------
// vtrans: v (N, DIM) fp32 -> vt bf16 [h][d][n]  (keys contiguous for PV frags)
// block = (64-key tile, head)
// ---------------------------------------------------------------------------
__global__ __launch_bounds__(256) void vtrans_kernel(
    const float* __restrict__ v, ushort* __restrict__ vt)
{
    __shared__ ushort L[64][68];
    const int kt = blockIdx.x, h = blockIdx.y, t = threadIdx.x;

    for (int e = t; e < 4096; e += 256) {
        int key = e >> 6, d = e & 63;          // d fast -> coalesced global read
        float f = v[(size_t)(kt * 64 + key) * DIM + h * DH + d];
        L[d][key] = f2bf(f);
    }
    __syncthreads();
    for (int e = t; e < 4096; e += 256) {
        int d = e >> 6, key = e & 63;          // key fast -> coalesced global write
        vt[((size_t)h * DH + d) * N_CTX + kt * 64 + key] = L[d][key];
    }
}

// ---------------------------------------------------------------------------
// attn: MFMA flash attention, fixed-max softmax (scores <= 12.5 by construction).
// Block: 128 queries x one head; K-tiles of 64. 4 waves.
//  S^T = K·Q^T  : wave w owns key-slice [w*16, w*16+16), all 128 queries.
//  O^T = V^T·P^T: wave w owns query-slice [w*32, w*32+32), all 64 d.
// All LDS fragment reads are ds_read_b128, rows padded to 72 bf16.
// ---------------------------------------------------------------------------
#define SC 0.18033688011112042f    // 0.125 * log2(e)
#define SB (-18.033688011112042f)  // -12.5 * log2(e)

__global__ __launch_bounds__(256) void attn_kernel(
    const ushort* __restrict__ qb, const ushort* __restrict__ kb,
    const ushort* __restrict__ vt, float* __restrict__ attn_out)
{
    __shared__ ushort Ks[64][72];    // [key][d]
    __shared__ ushort Vt[64][72];    // [d][key]
    __shared__ ushort Ps[128][72];   // [query][key]
    __shared__ float  Ls[4][128];    // per-wave l partials

    const int h     = blockIdx.y;
    const int qbase = blockIdx.x * 128;
    const int t    = threadIdx.x;
    const int w    = t >> 6;
    const int lane = t & 63;
    const int l15  = lane & 15;
    const int quad = lane >> 4;

    // preload Q B-fragments: B[n=query][k=d]; nt = query tile 0..7, ks = d-half
    bf16x8 qf[8][2];
    #pragma unroll
    for (int nt = 0; nt < 8; nt++)
        #pragma unroll
        for (int ks = 0; ks < 2; ks++)
            qf[nt][ks] = *(const bf16x8*)&qb[((size_t)h * N_CTX + qbase + nt * 16 + l15) * DH
                                             + ks * 32 + quad * 8];

    float l_part[8];
    f32x4 o_acc[4][2];
    #pragma unroll
    for (int nt = 0; nt < 8; nt++) l_part[nt] = 0.0f;
    #pragma unroll
    for (int dt = 0; dt < 4; dt++)
        #pragma unroll
        for (int qt = 0; qt < 2; qt++)
            o_acc[dt][qt] = (f32x4){0.f, 0.f, 0.f, 0.f};

    for (int kt = 0; kt < N_CTX / 64; kt++) {
        __syncthreads();   // prev iteration's PV done with Ks/Vt/Ps
        // stage K-tile and V^T-tile (coalesced b128 both sides, conflict-free)
        #pragma unroll
        for (int i = 0; i < 2; i++) {
            int c = t + i * 256, r = c >> 3, cb = c & 7;
            bf16x8 kk = *(const bf16x8*)&kb[((size_t)h * N_CTX + kt * 64 + r) * DH + cb * 8];
            *(bf16x8*)&Ks[r][cb * 8] = kk;
            bf16x8 vv = *(const bf16x8*)&vt[((size_t)h * DH + r) * N_CTX + kt * 64 + cb * 8];
            *(bf16x8*)&Vt[r][cb * 8] = vv;
        }
        __syncthreads();

        // S^T tile: A = K (m=key), B = Q^T; wave w -> keys w*16..+15
        bf16x8 kf0 = *(const bf16x8*)&Ks[w * 16 + l15][quad * 8];
        bf16x8 kf1 = *(const bf16x8*)&Ks[w * 16 + l15][32 + quad * 8];

        #pragma unroll
        for (int nt = 0; nt < 8; nt++) {
            f32x4 s = (f32x4){0.f, 0.f, 0.f, 0.f};
            s = __builtin_amdgcn_mfma_f32_16x16x32_bf16(kf0, qf[nt][0], s, 0, 0, 0);
            s = __builtin_amdgcn_mfma_f32_16x16x32_bf16(kf1, qf[nt][1], s, 0, 0, 0);

            // p = exp(0.125*s - 12.5) via exp2; accumulate l; pack bf16 -> Ps
            float p0, p1, p2, p3;
#if defined(__has_builtin) && __has_builtin(__builtin_amdgcn_exp2f)
            p0 = __builtin_amdgcn_exp2f(fmaf(s.x, SC, SB));
            p1 = __builtin_amdgcn_exp2f(fmaf(s.y, SC, SB));
            p2 = __builtin_amdgcn_exp2f(fmaf(s.z, SC, SB));
            p3 = __builtin_amdgcn_exp2f(fmaf(s.w, SC, SB));
#else
            p0 = exp2f(fmaf(s.x, SC, SB));
            p1 = exp2f(fmaf(s.y, SC, SB));
            p2 = exp2f(fmaf(s.z, SC, SB));
            p3 = exp2f(fmaf(s.w, SC, SB));
#endif
            l_part[nt] += (p0 + p1) + (p2 + p3);
            ushort4 pk;
            pk.x = f2bf(p0); pk.y = f2bf(p1); pk.z = f2bf(p2); pk.w = f2bf(p3);
            *(ushort4*)&Ps[nt * 16 + l15][w * 16 + quad * 4] = pk;
        }
        __syncthreads();   // Ps complete (cross-wave columns)

        // O^T: A = V^T (m=d), B = P^T (n=query); wave w -> queries w*32..+31
        #pragma unroll
        for (int ks = 0; ks < 2; ks++) {
            bf16x8 pf0 = *(const bf16x8*)&Ps[w * 32 + l15][ks * 32 + quad * 8];
            bf16x8 pf1 = *(const bf16x8*)&Ps[w * 32 + 16 + l15][ks * 32 + quad * 8];
            #pragma unroll
            for (int dt = 0; dt < 4; dt++) {
                bf16x8 vf = *(const bf16x8*)&Vt[dt * 16 + l15][ks * 32 + quad * 8];
                o_acc[dt][0] = __builtin_amdgcn_mfma_f32_16x16x32_bf16(vf, pf0, o_acc[dt][0], 0, 0, 0);
                o_acc[dt][1] = __builtin_amdgcn_mfma_f32_16x16x32_bf16(vf, pf1, o_acc[dt][1], 0, 0, 0);
            }
        }
    }

    // reduce l: sum over quads (shuffle), then across waves (LDS)
    #pragma unroll
    for (int nt = 0; nt < 8; nt++) {
        float v = l_part[nt];
        v += __shfl_xor(v, 16, 64);
        v += __shfl_xor(v, 32, 64);
        l_part[nt] = v;
    }
    if (quad == 0) {
        #pragma unroll
        for (int nt = 0; nt < 8; nt++) Ls[w][nt * 16 + l15] = l_part[nt];
    }
    __syncthreads();

    #pragma unroll
    for (int qt = 0; qt < 2; qt++) {
        int q = w * 32 + qt * 16 + l15;
        float linv = 1.0f / (((Ls[0][q] + Ls[1][q]) + (Ls[2][q] + Ls[3][q])));
        #pragma unroll
        for (int dt = 0; dt < 4; dt++) {
            f32x4 o = o_acc[dt][qt];
            float4 ov;
            ov.x = o.x * linv; ov.y = o.y * linv; ov.z = o.z * linv; ov.w = o.w * linv;
            *(float4*)&attn_out[(size_t)(qbase + q) * DIM + h * DH + dt * 16 + quad * 4] = ov;
        }
    }
}

// ---------------------------------------------------------------------------
// proj: out[n][o] = sum_c attn[n][c] * w[o][c] + b[o], fp32 (unchanged)
// ---------------------------------------------------------------------------
__global__ __launch_bounds__(256) void proj_kernel(
    const float* __restrict__ attn, const float* __restrict__ w,
    const float* __restrict__ bias, float* __restrict__ out)
{
    __shared__ float As[64][68];
    __shared__ float Ws[64][68];

    const int nbase = blockIdx.x * 64;
    const int obase = blockIdx.y * 64;
    const int t  = threadIdx.x;
    const int tr = t >> 4;
    const int tc = t & 15;
    const int i0 = tr * 4;
    const int j0 = tc * 4;

    float acc[4][4];
    #pragma unroll
    for (int a = 0; a < 4; a++)
        #pragma unroll
        for (int b = 0; b < 4; b++) acc[a][b] = 0.0f;

    for (int ct = 0; ct < DIM / 64; ct++) {
        __syncthreads();
        for (int e = t; e < 64 * 64; e += 256) {
            int r = e >> 6, cc = e & 63;
            As[r][cc] = attn[(size_t)(nbase + r) * DIM + ct * 64 + cc];
            Ws[r][cc] = w[(size_t)(obase + r) * DIM + ct * 64 + cc];
        }
        __syncthreads();

        for (int d = 0; d < 64; d += 4) {
            float4 av[4], wv[4];
            #pragma unroll
            for (int a = 0; a < 4; a++) av[a] = *(const float4*)&As[i0 + a][d];
            #pragma unroll
            for (int b = 0; b < 4; b++) wv[b] = *(const float4*)&Ws[j0 + b][d];
            #pragma unroll
            for (int a = 0; a < 4; a++)
                #pragma unroll
                for (int b = 0; b < 4; b++) {
                    acc[a][b] = fmaf(av[a].x, wv[b].x, acc[a][b]);
                    acc[a][b] = fmaf(av[a].y, wv[b].y, acc[a][b]);
                    acc[a][b] = fmaf(av[a].z, wv[b].z, acc[a][b]);
                    acc[a][b] = fmaf(av[a].w, wv[b].w, acc[a][b]);
                }
        }
    }

    #pragma unroll
    for (int a = 0; a < 4; a++)
        #pragma unroll
        for (int b = 0; b < 4; b++) {
            float bb = bias[obase + j0 + b];
            out[(size_t)(nbase + i0 + a) * DIM + obase + j0 + b] = acc[a][b] + bb;
        }
}

// ---------------------------------------------------------------------------
extern "C" void kernel_launch(void* const* d_in, const int* in_sizes, int n_in,
                              void* d_out, int out_size, void* d_ws, size_t ws_size,
                              hipStream_t stream)
{
    const float* q        = (const float*)d_in[0];
    const float* k        = (const float*)d_in[1];
    const float* v        = (const float*)d_in[2];
    const float* qk_scale = (const float*)d_in[3];
    const float* w_out    = (const float*)d_in[4];
    const float* b_out    = (const float*)d_in[5];
    float* out = (float*)d_out;

    const size_t per = (size_t)NH * N_CTX * DH;      // 4.19M elements
    ushort* qb  = (ushort*)d_ws;
    ushort* kb  = qb + per;
    ushort* vtg = kb + per;
    float*  attn = (float*)(vtg + per);              // (N, DIM) fp32, 16.8 MB

    prep_kernel<<<dim3(N_CTX * NH / 4), 256, 0, stream>>>(q, qk_scale, qb);
    prep_kernel<<<dim3(N_CTX * NH / 4), 256, 0, stream>>>(k, qk_scale, kb);
    vtrans_kernel<<<dim3(N_CTX / 64, NH), 256, 0, stream>>>(v, vtg);
    attn_kernel<<<dim3(N_CTX / 128, NH), 256, 0, stream>>>(qb, kb, vtg, attn);
    proj_kernel<<<dim3(N_CTX / 64, DIM / 64), 256, 0, stream>>>(attn, w_out, b_out, out);
}

// Round 5
// 320.470 us; speedup vs baseline: 4.9297x; 1.4287x over previous
//
#include <hip/hip_runtime.h>
#include <hip/hip_bf16.h>

#define N_CTX 4096
#define NH    16
#define DH    64
#define DIM   1024   // NH * DH

typedef __attribute__((ext_vector_type(8))) short bf16x8;  // 8 bf16 in 4 VGPRs
typedef __attribute__((ext_vector_type(4))) float f32x4;   // MFMA C/D

// RNE float->bf16 (bit manipulation, deterministic)
__device__ __forceinline__ ushort f2bf(float f) {
    union { float f; unsigned u; } x; x.f = f;
    unsigned r = (x.u + 0x7FFFu + ((x.u >> 16) & 1u)) >> 16;
    return (ushort)r;
}

// ---------------------------------------------------------------------------
// prep: x (N, DIM) fp32 -> rope -> l2norm -> * qk_scale -> xb bf16 [h][n][d]
// ---------------------------------------------------------------------------
__global__ __launch_bounds__(256) void prep_kernel(
    const float* __restrict__ x, const float* __restrict__ qk_scale,
    ushort* __restrict__ xb)
{
    const int lane = threadIdx.x & 63;
    const int wave = threadIdx.x >> 6;
    const int row  = blockIdx.x * 4 + wave;   // row = n*NH + h
    const int n = row >> 4;
    const int h = row & 15;

    float val = x[(size_t)n * DIM + h * DH + lane];
    float other = __shfl_xor(val, 1, 64);

    const int i = lane >> 1;
    float inv_freq = 1.0f / powf(10000.0f, (float)i * (1.0f / 32.0f));
    float ang = (float)n * inv_freq;
    float s, c;
    sincosf(ang, &s, &c);

    float r = (lane & 1) ? fmaf(other, s, val * c)
                         : fmaf(val, c, -(other * s));

    float ss = r * r;
    #pragma unroll
    for (int off = 32; off > 0; off >>= 1)
        ss += __shfl_xor(ss, off, 64);
    float invn = 1.0f / fmaxf(sqrtf(ss), 1e-12f);
    float scl  = qk_scale[lane];

    xb[((size_t)h * N_CTX + n) * DH + lane] = f2bf(r * invn * scl);
}

// ---------------------------------------------------------------------------
// vtrans: v (N, DIM) fp32 -> vt bf16 [h][d][n]
// ---------------------------------------------------------------------------
__global__ __launch_bounds__(256) void vtrans_kernel(
    const float* __restrict__ v, ushort* __restrict__ vt)
{
    __shared__ ushort L[64][68];
    const int kt = blockIdx.x, h = blockIdx.y, t = threadIdx.x;

    for (int e = t; e < 4096; e += 256) {
        int key = e >> 6, d = e & 63;
        float f = v[(size_t)(kt * 64 + key) * DIM + h * DH + d];
        L[d][key] = f2bf(f);
    }
    __syncthreads();
    for (int e = t; e < 4096; e += 256) {
        int d = e >> 6, key = e & 63;
        vt[((size_t)h * DH + d) * N_CTX + kt * 64 + key] = L[d][key];
    }
}

// ---------------------------------------------------------------------------
// wconv: w_out (DIM, DIM) fp32 -> bf16 row-major
// ---------------------------------------------------------------------------
__global__ __launch_bounds__(256) void wconv_kernel(
    const float* __restrict__ w, ushort* __restrict__ wb)
{
    int i = (blockIdx.x * 256 + threadIdx.x) * 4;
    float4 f = *(const float4*)&w[i];
    ushort4 u;
    u.x = f2bf(f.x); u.y = f2bf(f.y); u.z = f2bf(f.z); u.w = f2bf(f.w);
    *(ushort4*)&wb[i] = u;
}

// ---------------------------------------------------------------------------
// attn: MFMA flash attention, fixed-max softmax (scores <= 12.5).
// Block: 128 queries x one head; K-tiles of 64. bf16 output [n][DIM].
// ---------------------------------------------------------------------------
#define SC 0.18033688011112042f    // 0.125 * log2(e)
#define SB (-18.033688011112042f)  // -12.5 * log2(e)

__global__ __launch_bounds__(256) void attn_kernel(
    const ushort* __restrict__ qb, const ushort* __restrict__ kb,
    const ushort* __restrict__ vt, ushort* __restrict__ attn_out)
{
    __shared__ ushort Ks[64][72];    // [key][d]
    __shared__ ushort Vt[64][72];    // [d][key]
    __shared__ ushort Ps[128][72];   // [query][key]
    __shared__ float  Ls[4][128];    // per-wave l partials

    const int h     = blockIdx.y;
    const int qbase = blockIdx.x * 128;
    const int t    = threadIdx.x;
    const int w    = t >> 6;
    const int lane = t & 63;
    const int l15  = lane & 15;
    const int quad = lane >> 4;

    // preload Q B-fragments
    bf16x8 qf[8][2];
    #pragma unroll
    for (int nt = 0; nt < 8; nt++)
        #pragma unroll
        for (int ks = 0; ks < 2; ks++)
            qf[nt][ks] = *(const bf16x8*)&qb[((size_t)h * N_CTX + qbase + nt * 16 + l15) * DH
                                             + ks * 32 + quad * 8];

    float l_part[8];
    f32x4 o_acc[4][2];
    #pragma unroll
    for (int nt = 0; nt < 8; nt++) l_part[nt] = 0.0f;
    #pragma unroll
    for (int dt = 0; dt < 4; dt++)
        #pragma unroll
        for (int qt = 0; qt < 2; qt++)
            o_acc[dt][qt] = (f32x4){0.f, 0.f, 0.f, 0.f};

    for (int kt = 0; kt < N_CTX / 64; kt++) {
        __syncthreads();
        #pragma unroll
        for (int i = 0; i < 2; i++) {
            int c = t + i * 256, r = c >> 3, cb = c & 7;
            bf16x8 kk = *(const bf16x8*)&kb[((size_t)h * N_CTX + kt * 64 + r) * DH + cb * 8];
            *(bf16x8*)&Ks[r][cb * 8] = kk;
            bf16x8 vv = *(const bf16x8*)&vt[((size_t)h * DH + r) * N_CTX + kt * 64 + cb * 8];
            *(bf16x8*)&Vt[r][cb * 8] = vv;
        }
        __syncthreads();

        // S^T tile: A = K (m=key), B = Q^T; wave w -> keys w*16..+15
        bf16x8 kf0 = *(const bf16x8*)&Ks[w * 16 + l15][quad * 8];
        bf16x8 kf1 = *(const bf16x8*)&Ks[w * 16 + l15][32 + quad * 8];

        #pragma unroll
        for (int nt = 0; nt < 8; nt++) {
            f32x4 s = (f32x4){0.f, 0.f, 0.f, 0.f};
            s = __builtin_amdgcn_mfma_f32_16x16x32_bf16(kf0, qf[nt][0], s, 0, 0, 0);
            s = __builtin_amdgcn_mfma_f32_16x16x32_bf16(kf1, qf[nt][1], s, 0, 0, 0);

            float p0 = exp2f(fmaf(s.x, SC, SB));
            float p1 = exp2f(fmaf(s.y, SC, SB));
            float p2 = exp2f(fmaf(s.z, SC, SB));
            float p3 = exp2f(fmaf(s.w, SC, SB));
            l_part[nt] += (p0 + p1) + (p2 + p3);
            ushort4 pk;
            pk.x = f2bf(p0); pk.y = f2bf(p1); pk.z = f2bf(p2); pk.w = f2bf(p3);
            *(ushort4*)&Ps[nt * 16 + l15][w * 16 + quad * 4] = pk;
        }
        __syncthreads();

        // O^T: A = V^T (m=d), B = P^T (n=query); wave w -> queries w*32..+31
        #pragma unroll
        for (int ks = 0; ks < 2; ks++) {
            bf16x8 pf0 = *(const bf16x8*)&Ps[w * 32 + l15][ks * 32 + quad * 8];
            bf16x8 pf1 = *(const bf16x8*)&Ps[w * 32 + 16 + l15][ks * 32 + quad * 8];
            #pragma unroll
            for (int dt = 0; dt < 4; dt++) {
                bf16x8 vf = *(const bf16x8*)&Vt[dt * 16 + l15][ks * 32 + quad * 8];
                o_acc[dt][0] = __builtin_amdgcn_mfma_f32_16x16x32_bf16(vf, pf0, o_acc[dt][0], 0, 0, 0);
                o_acc[dt][1] = __builtin_amdgcn_mfma_f32_16x16x32_bf16(vf, pf1, o_acc[dt][1], 0, 0, 0);
            }
        }
    }

    // reduce l across quads and waves
    #pragma unroll
    for (int nt = 0; nt < 8; nt++) {
        float v = l_part[nt];
        v += __shfl_xor(v, 16, 64);
        v += __shfl_xor(v, 32, 64);
        l_part[nt] = v;
    }
    if (quad == 0) {
        #pragma unroll
        for (int nt = 0; nt < 8; nt++) Ls[w][nt * 16 + l15] = l_part[nt];
    }
    __syncthreads();

    #pragma unroll
    for (int qt = 0; qt < 2; qt++) {
        int q = w * 32 + qt * 16 + l15;
        float linv = 1.0f / (((Ls[0][q] + Ls[1][q]) + (Ls[2][q] + Ls[3][q])));
        #pragma unroll
        for (int dt = 0; dt < 4; dt++) {
            f32x4 o = o_acc[dt][qt];
            ushort4 ov;
            ov.x = f2bf(o.x * linv); ov.y = f2bf(o.y * linv);
            ov.z = f2bf(o.z * linv); ov.w = f2bf(o.w * linv);
            *(ushort4*)&attn_out[(size_t)(qbase + q) * DIM + h * DH + dt * 16 + quad * 4] = ov;
        }
    }
}

// ---------------------------------------------------------------------------
// proj (MFMA): out[n][o] = sum_c A[n][c] * W[o][c] + b[o]
// Block tile 128(n) x 64(o), BK=64, grid (32,16) = 512 blocks (2/CU).
// 4 waves in 2x2: wave w -> rows (w>>1)*64, cols (w&1)*32.
// ---------------------------------------------------------------------------
__global__ __launch_bounds__(256) void proj_kernel(
    const ushort* __restrict__ A, const ushort* __restrict__ W,
    const float* __restrict__ bias, float* __restrict__ out)
{
    __shared__ ushort As[128][72];
    __shared__ ushort Ws[64][72];

    const int nbase = blockIdx.x * 128;
    const int obase = blockIdx.y * 64;
    const int t    = threadIdx.x;
    const int w    = t >> 6;
    const int lane = t & 63;
    const int l15  = lane & 15;
    const int quad = lane >> 4;
    const int rw   = (w >> 1) * 64;   // wave row base in tile
    const int cw   = (w & 1) * 32;    // wave col base in tile

    f32x4 acc[4][2];
    #pragma unroll
    for (int mt = 0; mt < 4; mt++)
        #pragma unroll
        for (int nt = 0; nt < 2; nt++)
            acc[mt][nt] = (f32x4){0.f, 0.f, 0.f, 0.f};

    for (int kt = 0; kt < DIM / 64; kt++) {
        const int kb = kt * 64;
        __syncthreads();
        #pragma unroll
        for (int i = 0; i < 4; i++) {           // A tile: 128 rows x 64 k
            int c = t + i * 256, r = c >> 3, c8 = c & 7;
            *(bf16x8*)&As[r][c8 * 8] =
                *(const bf16x8*)&A[(size_t)(nbase + r) * DIM + kb + c8 * 8];
        }
        #pragma unroll
        for (int i = 0; i < 2; i++) {           // W tile: 64 rows x 64 k
            int c = t + i * 256, r = c >> 3, c8 = c & 7;
            *(bf16x8*)&Ws[r][c8 * 8] =
                *(const bf16x8*)&W[(size_t)(obase + r) * DIM + kb + c8 * 8];
        }
        __syncthreads();

        bf16x8 af[4][2], bfr[2][2];
        #pragma unroll
        for (int mt = 0; mt < 4; mt++)
            #pragma unroll
            for (int kh = 0; kh < 2; kh++)
                af[mt][kh] = *(const bf16x8*)&As[rw + mt * 16 + l15][kh * 32 + quad * 8];
        #pragma unroll
        for (int nt = 0; nt < 2; nt++)
            #pragma unroll
            for (int kh = 0; kh < 2; kh++)
                bfr[nt][kh] = *(const bf16x8*)&Ws[cw + nt * 16 + l15][kh * 32 + quad * 8];

        #pragma unroll
        for (int mt = 0; mt < 4; mt++)
            #pragma unroll
            for (int nt = 0; nt < 2; nt++) {
                acc[mt][nt] = __builtin_amdgcn_mfma_f32_16x16x32_bf16(af[mt][0], bfr[nt][0], acc[mt][nt], 0, 0, 0);
                acc[mt][nt] = __builtin_amdgcn_mfma_f32_16x16x32_bf16(af[mt][1], bfr[nt][1], acc[mt][nt], 0, 0, 0);
            }
    }

    // epilogue: C layout col(l15)=o, row(quad*4+r)=n
    #pragma unroll
    for (int nt = 0; nt < 2; nt++) {
        int o = obase + cw + nt * 16 + l15;
        float bb = bias[o];
        #pragma unroll
        for (int mt = 0; mt < 4; mt++) {
            int nrow = nbase + rw + mt * 16 + quad * 4;
            out[(size_t)(nrow + 0) * DIM + o] = acc[mt][nt].x + bb;
            out[(size_t)(nrow + 1) * DIM + o] = acc[mt][nt].y + bb;
            out[(size_t)(nrow + 2) * DIM + o] = acc[mt][nt].z + bb;
            out[(size_t)(nrow + 3) * DIM + o] = acc[mt][nt].w + bb;
        }
    }
}

// ---------------------------------------------------------------------------
extern "C" void kernel_launch(void* const* d_in, const int* in_sizes, int n_in,
                              void* d_out, int out_size, void* d_ws, size_t ws_size,
                              hipStream_t stream)
{
    const float* q        = (const float*)d_in[0];
    const float* k        = (const float*)d_in[1];
    const float* v        = (const float*)d_in[2];
    const float* qk_scale = (const float*)d_in[3];
    const float* w_out    = (const float*)d_in[4];
    const float* b_out    = (const float*)d_in[5];
    float* out = (float*)d_out;

    const size_t per = (size_t)NH * N_CTX * DH;      // 4.19M elements
    ushort* qb    = (ushort*)d_ws;
    ushort* kb    = qb + per;
    ushort* vtg   = kb + per;
    ushort* attnb = vtg + per;                       // (N, DIM) bf16, 8.4 MB
    ushort* wb    = attnb + per;                     // (DIM, DIM) bf16, 2.1 MB

    prep_kernel<<<dim3(N_CTX * NH / 4), 256, 0, stream>>>(q, qk_scale, qb);
    prep_kernel<<<dim3(N_CTX * NH / 4), 256, 0, stream>>>(k, qk_scale, kb);
    vtrans_kernel<<<dim3(N_CTX / 64, NH), 256, 0, stream>>>(v, vtg);
    wconv_kernel<<<dim3(DIM * DIM / 1024), 256, 0, stream>>>(w_out, wb);
    attn_kernel<<<dim3(N_CTX / 128, NH), 256, 0, stream>>>(qb, kb, vtg, attnb);
    proj_kernel<<<dim3(N_CTX / 128, DIM / 64), 256, 0, stream>>>(attnb, wb, b_out, out);
}

// Round 6
// 291.042 us; speedup vs baseline: 5.4282x; 1.1011x over previous
//
#include <hip/hip_runtime.h>
#include <hip/hip_bf16.h>

#define N_CTX 4096
#define NH    16
#define DH    64
#define DIM   1024   // NH * DH

typedef __attribute__((ext_vector_type(8))) short bf16x8;  // 8 bf16 in 4 VGPRs
typedef __attribute__((ext_vector_type(4))) float f32x4;   // MFMA C/D

// RNE float->bf16 (used in non-hot kernels)
__device__ __forceinline__ ushort f2bf(float f) {
    union { float f; unsigned u; } x; x.f = f;
    unsigned r = (x.u + 0x7FFFu + ((x.u >> 16) & 1u)) >> 16;
    return (ushort)r;
}
// round-half-up float->bf16: 2 VALU ops, same 0.5-ulp bound as RNE
__device__ __forceinline__ ushort f2bf_fast(float f) {
    union { float f; unsigned u; } x; x.f = f;
    return (ushort)((x.u + 0x8000u) >> 16);
}

// ---------------------------------------------------------------------------
// prep: x (N, DIM) fp32 -> rope -> l2norm -> * qk_scale -> xb bf16 [h][n][d]
// ---------------------------------------------------------------------------
__global__ __launch_bounds__(256) void prep_kernel(
    const float* __restrict__ x, const float* __restrict__ qk_scale,
    ushort* __restrict__ xb)
{
    const int lane = threadIdx.x & 63;
    const int wave = threadIdx.x >> 6;
    const int row  = blockIdx.x * 4 + wave;   // row = n*NH + h
    const int n = row >> 4;
    const int h = row & 15;

    float val = x[(size_t)n * DIM + h * DH + lane];
    float other = __shfl_xor(val, 1, 64);

    const int i = lane >> 1;
    float inv_freq = 1.0f / powf(10000.0f, (float)i * (1.0f / 32.0f));
    float ang = (float)n * inv_freq;
    float s, c;
    sincosf(ang, &s, &c);

    float r = (lane & 1) ? fmaf(other, s, val * c)
                         : fmaf(val, c, -(other * s));

    float ss = r * r;
    #pragma unroll
    for (int off = 32; off > 0; off >>= 1)
        ss += __shfl_xor(ss, off, 64);
    float invn = 1.0f / fmaxf(sqrtf(ss), 1e-12f);
    float scl  = qk_scale[lane];

    xb[((size_t)h * N_CTX + n) * DH + lane] = f2bf(r * invn * scl);
}

// ---------------------------------------------------------------------------
// vtrans: v (N, DIM) fp32 -> vt bf16 [h][d][n]
// ---------------------------------------------------------------------------
__global__ __launch_bounds__(256) void vtrans_kernel(
    const float* __restrict__ v, ushort* __restrict__ vt)
{
    __shared__ ushort L[64][68];
    const int kt = blockIdx.x, h = blockIdx.y, t = threadIdx.x;

    for (int e = t; e < 4096; e += 256) {
        int key = e >> 6, d = e & 63;
        float f = v[(size_t)(kt * 64 + key) * DIM + h * DH + d];
        L[d][key] = f2bf(f);
    }
    __syncthreads();
    for (int e = t; e < 4096; e += 256) {
        int d = e >> 6, key = e & 63;
        vt[((size_t)h * DH + d) * N_CTX + kt * 64 + key] = L[d][key];
    }
}

// ---------------------------------------------------------------------------
// wconv: w_out (DIM, DIM) fp32 -> bf16 row-major
// ---------------------------------------------------------------------------
__global__ __launch_bounds__(256) void wconv_kernel(
    const float* __restrict__ w, ushort* __restrict__ wb)
{
    int i = (blockIdx.x * 256 + threadIdx.x) * 4;
    float4 f = *(const float4*)&w[i];
    ushort4 u;
    u.x = f2bf(f.x); u.y = f2bf(f.y); u.z = f2bf(f.z); u.w = f2bf(f.w);
    *(ushort4*)&wb[i] = u;
}

// ---------------------------------------------------------------------------
// attn: MFMA flash attention, fixed-max softmax (scores <= 12.5).
// Block: 128 queries x one head, 512 threads (8 waves). K-tiles of 64.
//  S^T = K·Q^T : wave w -> keys (w&3)*16..+16, queries (w>>2)*64..+64
//  O^T = V^T·P^T: wave w -> queries w*16..+16, all 64 d
// ---------------------------------------------------------------------------
#define SC 0.18033688011112042f    // 0.125 * log2(e)
#define SB (-18.033688011112042f)  // -12.5 * log2(e)

__global__ __launch_bounds__(512) void attn_kernel(
    const ushort* __restrict__ qb, const ushort* __restrict__ kb,
    const ushort* __restrict__ vt, ushort* __restrict__ attn_out)
{
    __shared__ ushort Ks[64][72];    // [key][d]
    __shared__ ushort Vt[64][72];    // [d][key]
    __shared__ ushort Ps[128][72];   // [query][key]
    __shared__ float  Ls[4][128];    // [key-slice][query] l partials

    const int h     = blockIdx.y;
    const int qbase = blockIdx.x * 128;
    const int t      = threadIdx.x;
    const int w      = t >> 6;
    const int lane   = t & 63;
    const int l15    = lane & 15;
    const int quad   = lane >> 4;
    const int kslice = (w & 3) * 16;   // S-phase key slice
    const int qhalf  = (w >> 2) * 64;  // S-phase query half

    // preload Q B-fragments for this wave's query half: 4 tiles x 2 k-halves
    bf16x8 qf[4][2];
    #pragma unroll
    for (int nt = 0; nt < 4; nt++)
        #pragma unroll
        for (int ks = 0; ks < 2; ks++)
            qf[nt][ks] = *(const bf16x8*)&qb[((size_t)h * N_CTX + qbase + qhalf + nt * 16 + l15) * DH
                                             + ks * 32 + quad * 8];

    float l_part[4];
    f32x4 o_acc[4];
    #pragma unroll
    for (int nt = 0; nt < 4; nt++) l_part[nt] = 0.0f;
    #pragma unroll
    for (int dt = 0; dt < 4; dt++) o_acc[dt] = (f32x4){0.f, 0.f, 0.f, 0.f};

    for (int kt = 0; kt < N_CTX / 64; kt++) {
        __syncthreads();   // prev iteration's PV done with Ks/Vt/Ps
        // stage K-tile and V^T-tile: 512 threads, one 16B chunk each
        {
            int r = t >> 3, c8 = t & 7;
            *(bf16x8*)&Ks[r][c8 * 8] =
                *(const bf16x8*)&kb[((size_t)h * N_CTX + kt * 64 + r) * DH + c8 * 8];
            *(bf16x8*)&Vt[r][c8 * 8] =
                *(const bf16x8*)&vt[((size_t)h * DH + r) * N_CTX + kt * 64 + c8 * 8];
        }
        __syncthreads();

        // S^T tile: A = K (m=key), B = Q^T (n=query)
        bf16x8 kf0 = *(const bf16x8*)&Ks[kslice + l15][quad * 8];
        bf16x8 kf1 = *(const bf16x8*)&Ks[kslice + l15][32 + quad * 8];

        #pragma unroll
        for (int nt = 0; nt < 4; nt++) {
            f32x4 s = (f32x4){0.f, 0.f, 0.f, 0.f};
            s = __builtin_amdgcn_mfma_f32_16x16x32_bf16(kf0, qf[nt][0], s, 0, 0, 0);
            s = __builtin_amdgcn_mfma_f32_16x16x32_bf16(kf1, qf[nt][1], s, 0, 0, 0);

            float p0 = exp2f(fmaf(s.x, SC, SB));
            float p1 = exp2f(fmaf(s.y, SC, SB));
            float p2 = exp2f(fmaf(s.z, SC, SB));
            float p3 = exp2f(fmaf(s.w, SC, SB));
            l_part[nt] += (p0 + p1) + (p2 + p3);
            ushort4 pk;
            pk.x = f2bf_fast(p0); pk.y = f2bf_fast(p1);
            pk.z = f2bf_fast(p2); pk.w = f2bf_fast(p3);
            *(ushort4*)&Ps[qhalf + nt * 16 + l15][kslice + quad * 4] = pk;
        }
        __syncthreads();   // Ps complete (cross-wave)

        // O^T: A = V^T (m=d), B = P^T (n=query); wave w -> queries w*16..+16
        #pragma unroll
        for (int ks = 0; ks < 2; ks++) {
            bf16x8 pf = *(const bf16x8*)&Ps[w * 16 + l15][ks * 32 + quad * 8];
            #pragma unroll
            for (int dt = 0; dt < 4; dt++) {
                bf16x8 vf = *(const bf16x8*)&Vt[dt * 16 + l15][ks * 32 + quad * 8];
                o_acc[dt] = __builtin_amdgcn_mfma_f32_16x16x32_bf16(vf, pf, o_acc[dt], 0, 0, 0);
            }
        }
    }

    // reduce l over quads (in-wave), publish per-key-slice partials
    #pragma unroll
    for (int nt = 0; nt < 4; nt++) {
        float v = l_part[nt];
        v += __shfl_xor(v, 16, 64);
        v += __shfl_xor(v, 32, 64);
        l_part[nt] = v;
    }
    if (quad == 0) {
        #pragma unroll
        for (int nt = 0; nt < 4; nt++)
            Ls[w & 3][qhalf + nt * 16 + l15] = l_part[nt];
    }
    __syncthreads();

    // epilogue: wave w owns queries w*16..+16
    {
        int q = w * 16 + l15;
        float linv = 1.0f / ((Ls[0][q] + Ls[1][q]) + (Ls[2][q] + Ls[3][q]));
        #pragma unroll
        for (int dt = 0; dt < 4; dt++) {
            f32x4 o = o_acc[dt];
            ushort4 ov;
            ov.x = f2bf_fast(o.x * linv); ov.y = f2bf_fast(o.y * linv);
            ov.z = f2bf_fast(o.z * linv); ov.w = f2bf_fast(o.w * linv);
            *(ushort4*)&attn_out[(size_t)(qbase + q) * DIM + h * DH + dt * 16 + quad * 4] = ov;
        }
    }
}

// ---------------------------------------------------------------------------
// proj (MFMA): out[n][o] = sum_c A[n][c] * W[o][c] + b[o]
// Block tile 128(n) x 64(o), BK=64, grid (32,16) = 512 blocks.
// ---------------------------------------------------------------------------
__global__ __launch_bounds__(256) void proj_kernel(
    const ushort* __restrict__ A, const ushort* __restrict__ W,
    const float* __restrict__ bias, float* __restrict__ out)
{
    __shared__ ushort As[128][72];
    __shared__ ushort Ws[64][72];

    const int nbase = blockIdx.x * 128;
    const int obase = blockIdx.y * 64;
    const int t    = threadIdx.x;
    const int w    = t >> 6;
    const int lane = t & 63;
    const int l15  = lane & 15;
    const int quad = lane >> 4;
    const int rw   = (w >> 1) * 64;
    const int cw   = (w & 1) * 32;

    f32x4 acc[4][2];
    #pragma unroll
    for (int mt = 0; mt < 4; mt++)
        #pragma unroll
        for (int nt = 0; nt < 2; nt++)
            acc[mt][nt] = (f32x4){0.f, 0.f, 0.f, 0.f};

    for (int kt = 0; kt < DIM / 64; kt++) {
        const int kb = kt * 64;
        __syncthreads();
        #pragma unroll
        for (int i = 0; i < 4; i++) {
            int c = t + i * 256, r = c >> 3, c8 = c & 7;
            *(bf16x8*)&As[r][c8 * 8] =
                *(const bf16x8*)&A[(size_t)(nbase + r) * DIM + kb + c8 * 8];
        }
        #pragma unroll
        for (int i = 0; i < 2; i++) {
            int c = t + i * 256, r = c >> 3, c8 = c & 7;
            *(bf16x8*)&Ws[r][c8 * 8] =
                *(const bf16x8*)&W[(size_t)(obase + r) * DIM + kb + c8 * 8];
        }
        __syncthreads();

        bf16x8 af[4][2], bfr[2][2];
        #pragma unroll
        for (int mt = 0; mt < 4; mt++)
            #pragma unroll
            for (int kh = 0; kh < 2; kh++)
                af[mt][kh] = *(const bf16x8*)&As[rw + mt * 16 + l15][kh * 32 + quad * 8];
        #pragma unroll
        for (int nt = 0; nt < 2; nt++)
            #pragma unroll
            for (int kh = 0; kh < 2; kh++)
                bfr[nt][kh] = *(const bf16x8*)&Ws[cw + nt * 16 + l15][kh * 32 + quad * 8];

        #pragma unroll
        for (int mt = 0; mt < 4; mt++)
            #pragma unroll
            for (int nt = 0; nt < 2; nt++) {
                acc[mt][nt] = __builtin_amdgcn_mfma_f32_16x16x32_bf16(af[mt][0], bfr[nt][0], acc[mt][nt], 0, 0, 0);
                acc[mt][nt] = __builtin_amdgcn_mfma_f32_16x16x32_bf16(af[mt][1], bfr[nt][1], acc[mt][nt], 0, 0, 0);
            }
    }

    #pragma unroll
    for (int nt = 0; nt < 2; nt++) {
        int o = obase + cw + nt * 16 + l15;
        float bb = bias[o];
        #pragma unroll
        for (int mt = 0; mt < 4; mt++) {
            int nrow = nbase + rw + mt * 16 + quad * 4;
            out[(size_t)(nrow + 0) * DIM + o] = acc[mt][nt].x + bb;
            out[(size_t)(nrow + 1) * DIM + o] = acc[mt][nt].y + bb;
            out[(size_t)(nrow + 2) * DIM + o] = acc[mt][nt].z + bb;
            out[(size_t)(nrow + 3) * DIM + o] = acc[mt][nt].w + bb;
        }
    }
}

// ---------------------------------------------------------------------------
extern "C" void kernel_launch(void* const* d_in, const int* in_sizes, int n_in,
                              void* d_out, int out_size, void* d_ws, size_t ws_size,
                              hipStream_t stream)
{
    const float* q        = (const float*)d_in[0];
    const float* k        = (const float*)d_in[1];
    const float* v        = (const float*)d_in[2];
    const float* qk_scale = (const float*)d_in[3];
    const float* w_out    = (const float*)d_in[4];
    const float* b_out    = (const float*)d_in[5];
    float* out = (float*)d_out;

    const size_t per = (size_t)NH * N_CTX * DH;      // 4.19M elements
    ushort* qb    = (ushort*)d_ws;
    ushort* kb    = qb + per;
    ushort* vtg   = kb + per;
    ushort* attnb = vtg + per;                       // (N, DIM) bf16
    ushort* wb    = attnb + per;                     // (DIM, DIM) bf16

    prep_kernel<<<dim3(N_CTX * NH / 4), 256, 0, stream>>>(q, qk_scale, qb);
    prep_kernel<<<dim3(N_CTX * NH / 4), 256, 0, stream>>>(k, qk_scale, kb);
    vtrans_kernel<<<dim3(N_CTX / 64, NH), 256, 0, stream>>>(v, vtg);
    wconv_kernel<<<dim3(DIM * DIM / 1024), 256, 0, stream>>>(w_out, wb);
    attn_kernel<<<dim3(N_CTX / 128, NH), 512, 0, stream>>>(qb, kb, vtg, attnb);
    proj_kernel<<<dim3(N_CTX / 128, DIM / 64), 256, 0, stream>>>(attnb, wb, b_out, out);
}

// Round 7
// 274.470 us; speedup vs baseline: 5.7559x; 1.0604x over previous
//
#include <hip/hip_runtime.h>
#include <hip/hip_bf16.h>

#define N_CTX 4096
#define NH    16
#define DH    64
#define DIM   1024   // NH * DH
#define NSPLIT 2
#define KT_PER_SPLIT (N_CTX / 64 / NSPLIT)   // 32

typedef __attribute__((ext_vector_type(8))) short bf16x8;  // 8 bf16 in 4 VGPRs
typedef __attribute__((ext_vector_type(4))) float f32x4;   // MFMA C/D

// RNE float->bf16 (non-hot paths)
__device__ __forceinline__ ushort f2bf(float f) {
    union { float f; unsigned u; } x; x.f = f;
    unsigned r = (x.u + 0x7FFFu + ((x.u >> 16) & 1u)) >> 16;
    return (ushort)r;
}
__device__ __forceinline__ unsigned fbits(float f) {
    union { float f; unsigned u; } x; x.f = f; return x.u;
}
// pack two floats to packed bf16 pair (round-half-up), 3 VALU ops
__device__ __forceinline__ unsigned pack_bf16(float lo, float hi) {
    unsigned a = fbits(lo) + 0x8000u;
    unsigned b = fbits(hi) + 0x8000u;
#if defined(__has_builtin)
#if __has_builtin(__builtin_amdgcn_perm)
    return __builtin_amdgcn_perm(b, a, 0x07060302u);
#else
    return (a >> 16) | (b & 0xFFFF0000u);
#endif
#else
    return (a >> 16) | (b & 0xFFFF0000u);
#endif
}
__device__ __forceinline__ float fast_exp2(float x) {
#if defined(__has_builtin)
#if __has_builtin(__builtin_amdgcn_exp2f)
    return __builtin_amdgcn_exp2f(x);
#else
    return exp2f(x);
#endif
#else
    return exp2f(x);
#endif
}

// ---------------------------------------------------------------------------
// prep: x (N, DIM) fp32 -> rope -> l2norm -> * qk_scale -> xb bf16 [h][n][d]
// ---------------------------------------------------------------------------
__global__ __launch_bounds__(256) void prep_kernel(
    const float* __restrict__ x, const float* __restrict__ qk_scale,
    ushort* __restrict__ xb)
{
    const int lane = threadIdx.x & 63;
    const int wave = threadIdx.x >> 6;
    const int row  = blockIdx.x * 4 + wave;   // row = n*NH + h
    const int n = row >> 4;
    const int h = row & 15;

    float val = x[(size_t)n * DIM + h * DH + lane];
    float other = __shfl_xor(val, 1, 64);

    const int i = lane >> 1;
    float inv_freq = 1.0f / powf(10000.0f, (float)i * (1.0f / 32.0f));
    float ang = (float)n * inv_freq;
    float s, c;
    sincosf(ang, &s, &c);

    float r = (lane & 1) ? fmaf(other, s, val * c)
                         : fmaf(val, c, -(other * s));

    float ss = r * r;
    #pragma unroll
    for (int off = 32; off > 0; off >>= 1)
        ss += __shfl_xor(ss, off, 64);
    float invn = 1.0f / fmaxf(sqrtf(ss), 1e-12f);
    float scl  = qk_scale[lane];

    xb[((size_t)h * N_CTX + n) * DH + lane] = f2bf(r * invn * scl);
}

// ---------------------------------------------------------------------------
// vtrans: v (N, DIM) fp32 -> vt bf16 [h][d][n]
// ---------------------------------------------------------------------------
__global__ __launch_bounds__(256) void vtrans_kernel(
    const float* __restrict__ v, ushort* __restrict__ vt)
{
    __shared__ ushort L[64][68];
    const int kt = blockIdx.x, h = blockIdx.y, t = threadIdx.x;

    for (int e = t; e < 4096; e += 256) {
        int key = e >> 6, d = e & 63;
        float f = v[(size_t)(kt * 64 + key) * DIM + h * DH + d];
        L[d][key] = f2bf(f);
    }
    __syncthreads();
    for (int e = t; e < 4096; e += 256) {
        int d = e >> 6, key = e & 63;
        vt[((size_t)h * DH + d) * N_CTX + kt * 64 + key] = L[d][key];
    }
}

// ---------------------------------------------------------------------------
// wconv: w_out (DIM, DIM) fp32 -> bf16 row-major
// ---------------------------------------------------------------------------
__global__ __launch_bounds__(256) void wconv_kernel(
    const float* __restrict__ w, ushort* __restrict__ wb)
{
    int i = (blockIdx.x * 256 + threadIdx.x) * 4;
    float4 f = *(const float4*)&w[i];
    ushort4 u;
    u.x = f2bf(f.x); u.y = f2bf(f.y); u.z = f2bf(f.z); u.w = f2bf(f.w);
    *(ushort4*)&wb[i] = u;
}

// ---------------------------------------------------------------------------
// attn: MFMA flash attention, fixed-max softmax (scores <= 12.5), split-K.
// Block: 128 queries x head x split(2048 keys), 512 threads (8 waves).
// Wave w owns queries w*16..+16 END-TO-END: S over all 64 keys of the tile,
// P roundtrip through its own Ps rows (same-wave, no barrier), PV, own l.
// 2 barriers/ktile (single-buffer staging); staging loads issued post-B.
// Outputs fp32 O-partials (pre-division) + l-partials; combine_kernel sums.
// ---------------------------------------------------------------------------
#define SC 0.18033688011112042f    // 0.125 * log2(e)
#define SB (-18.033688011112042f)  // -12.5 * log2(e)

__global__ __launch_bounds__(512) void attn_kernel(
    const ushort* __restrict__ qb, const ushort* __restrict__ kb,
    const ushort* __restrict__ vt, float* __restrict__ opart,
    float* __restrict__ lpart)
{
    __shared__ ushort Ks[64][72];    // [key][d]
    __shared__ ushort Vt[64][72];    // [d][key]
    __shared__ ushort Ps[128][72];   // [query][key], rows w*16..+16 per wave

    const int h     = blockIdx.y;
    const int qbase = blockIdx.x * 128;
    const int sp    = blockIdx.z;
    const int kbase = sp * (N_CTX / NSPLIT);
    const int t    = threadIdx.x;
    const int w    = t >> 6;
    const int lane = t & 63;
    const int l15  = lane & 15;
    const int quad = lane >> 4;

    // Q B-fragments for this wave's 16 queries (2 k-halves)
    const size_t qrow = ((size_t)h * N_CTX + qbase + w * 16 + l15) * DH;
    bf16x8 qf0 = *(const bf16x8*)&qb[qrow + quad * 8];
    bf16x8 qf1 = *(const bf16x8*)&qb[qrow + 32 + quad * 8];

    float l_part = 0.0f;
    f32x4 o_acc[4];
    #pragma unroll
    for (int dt = 0; dt < 4; dt++) o_acc[dt] = (f32x4){0.f, 0.f, 0.f, 0.f};

    // staging: thread t handles row sr, 8-elem chunk sc
    const int sr = t >> 3;
    const int sc = (t & 7) * 8;
    const ushort* kptr = &kb[((size_t)h * N_CTX + kbase + sr) * DH + sc];
    const ushort* vptr = &vt[((size_t)h * DH + sr) * N_CTX + kbase + sc];
    bf16x8 kreg = *(const bf16x8*)kptr;
    bf16x8 vreg = *(const bf16x8*)vptr;

    for (int kt = 0; kt < KT_PER_SPLIT; kt++) {
        __syncthreads();                     // A: all waves done with prev tile
        *(bf16x8*)&Ks[sr][sc] = kreg;
        *(bf16x8*)&Vt[sr][sc] = vreg;
        __syncthreads();                     // B: staging visible
        if (kt + 1 < KT_PER_SPLIT) {         // issue next loads; they drain at
            kreg = *(const bf16x8*)(kptr + (size_t)(kt + 1) * 64 * DH);  // next A
            vreg = *(const bf16x8*)(vptr + (size_t)(kt + 1) * 64);
        }

        // ---- S phase: 4 key-tiles of 16, all for this wave's 16 queries
        #pragma unroll
        for (int j = 0; j < 4; j++) {
            bf16x8 kf0 = *(const bf16x8*)&Ks[j * 16 + l15][quad * 8];
            bf16x8 kf1 = *(const bf16x8*)&Ks[j * 16 + l15][32 + quad * 8];
            f32x4 s = (f32x4){0.f, 0.f, 0.f, 0.f};
            s = __builtin_amdgcn_mfma_f32_16x16x32_bf16(kf0, qf0, s, 0, 0, 0);
            s = __builtin_amdgcn_mfma_f32_16x16x32_bf16(kf1, qf1, s, 0, 0, 0);

            float p0 = fast_exp2(fmaf(s.x, SC, SB));
            float p1 = fast_exp2(fmaf(s.y, SC, SB));
            float p2 = fast_exp2(fmaf(s.z, SC, SB));
            float p3 = fast_exp2(fmaf(s.w, SC, SB));
            l_part += (p0 + p1) + (p2 + p3);
            uint2 pk;
            pk.x = pack_bf16(p0, p1);
            pk.y = pack_bf16(p2, p3);
            *(uint2*)&Ps[w * 16 + l15][j * 16 + quad * 4] = pk;
        }

        // ---- PV phase: same wave reads its own Ps rows (lgkmcnt-ordered)
        #pragma unroll
        for (int ks = 0; ks < 2; ks++) {
            bf16x8 pf = *(const bf16x8*)&Ps[w * 16 + l15][ks * 32 + quad * 8];
            #pragma unroll
            for (int dt = 0; dt < 4; dt++) {
                bf16x8 vf = *(const bf16x8*)&Vt[dt * 16 + l15][ks * 32 + quad * 8];
                o_acc[dt] = __builtin_amdgcn_mfma_f32_16x16x32_bf16(vf, pf, o_acc[dt], 0, 0, 0);
            }
        }
    }

    // l: reduce across quads (each quad holds a disjoint key-subset partial)
    l_part += __shfl_xor(l_part, 16, 64);
    l_part += __shfl_xor(l_part, 32, 64);
    if (quad == 0)
        lpart[(size_t)sp * NH * N_CTX + (size_t)h * N_CTX + qbase + w * 16 + l15] = l_part;

    // O partial (pre-division), fp32 (N, DIM) layout per split
    #pragma unroll
    for (int dt = 0; dt < 4; dt++) {
        f32x4 o = o_acc[dt];
        float4 ov; ov.x = o.x; ov.y = o.y; ov.z = o.z; ov.w = o.w;
        *(float4*)&opart[((size_t)sp * N_CTX + qbase + w * 16 + l15) * DIM
                         + h * DH + dt * 16 + quad * 4] = ov;
    }
}

// ---------------------------------------------------------------------------
// combine: attnb[n][c] = bf16( (O0+O1)[n][c] / (l0+l1)[n,h] )
// ---------------------------------------------------------------------------
__global__ __launch_bounds__(256) void combine_kernel(
    const float* __restrict__ opart, const float* __restrict__ lpart,
    ushort* __restrict__ attnb)
{
    const int idx = blockIdx.x * 256 + threadIdx.x;   // one per 4 elements
    const int n   = idx >> 8;                         // DIM/4 = 256 groups/row
    const int rem = idx & 255;
    const int h   = rem >> 4;                         // 16 groups per head
    const size_t e = (size_t)n * DIM + h * DH + (rem & 15) * 4;

    float4 o0 = *(const float4*)&opart[e];
    float4 o1 = *(const float4*)&opart[(size_t)N_CTX * DIM + e];
    float l0 = lpart[(size_t)h * N_CTX + n];
    float l1 = lpart[(size_t)NH * N_CTX + (size_t)h * N_CTX + n];
    float li = 1.0f / (l0 + l1);

    ushort4 r;
    r.x = f2bf((o0.x + o1.x) * li);
    r.y = f2bf((o0.y + o1.y) * li);
    r.z = f2bf((o0.z + o1.z) * li);
    r.w = f2bf((o0.w + o1.w) * li);
    *(ushort4*)&attnb[e] = r;
}

// ---------------------------------------------------------------------------
// proj (MFMA): out[n][o] = sum_c A[n][c] * W[o][c] + b[o]   (unchanged)
// ---------------------------------------------------------------------------
__global__ __launch_bounds__(256) void proj_kernel(
    const ushort* __restrict__ A, const ushort* __restrict__ W,
    const float* __restrict__ bias, float* __restrict__ out)
{
    __shared__ ushort As[128][72];
    __shared__ ushort Ws[64][72];

    const int nbase = blockIdx.x * 128;
    const int obase = blockIdx.y * 64;
    const int t    = threadIdx.x;
    const int w    = t >> 6;
    const int lane = t & 63;
    const int l15  = lane & 15;
    const int quad = lane >> 4;
    const int rw   = (w >> 1) * 64;
    const int cw   = (w & 1) * 32;

    f32x4 acc[4][2];
    #pragma unroll
    for (int mt = 0; mt < 4; mt++)
        #pragma unroll
        for (int nt = 0; nt < 2; nt++)
            acc[mt][nt] = (f32x4){0.f, 0.f, 0.f, 0.f};

    for (int kt = 0; kt < DIM / 64; kt++) {
        const int kb = kt * 64;
        __syncthreads();
        #pragma unroll
        for (int i = 0; i < 4; i++) {
            int c = t + i * 256, r = c >> 3, c8 = c & 7;
            *(bf16x8*)&As[r][c8 * 8] =
                *(const bf16x8*)&A[(size_t)(nbase + r) * DIM + kb + c8 * 8];
        }
        #pragma unroll
        for (int i = 0; i < 2; i++) {
            int c = t + i * 256, r = c >> 3, c8 = c & 7;
            *(bf16x8*)&Ws[r][c8 * 8] =
                *(const bf16x8*)&W[(size_t)(obase + r) * DIM + kb + c8 * 8];
        }
        __syncthreads();

        bf16x8 af[4][2], bfr[2][2];
        #pragma unroll
        for (int mt = 0; mt < 4; mt++)
            #pragma unroll
            for (int kh = 0; kh < 2; kh++)
                af[mt][kh] = *(const bf16x8*)&As[rw + mt * 16 + l15][kh * 32 + quad * 8];
        #pragma unroll
        for (int nt = 0; nt < 2; nt++)
            #pragma unroll
            for (int kh = 0; kh < 2; kh++)
                bfr[nt][kh] = *(const bf16x8*)&Ws[cw + nt * 16 + l15][kh * 32 + quad * 8];

        #pragma unroll
        for (int mt = 0; mt < 4; mt++)
            #pragma unroll
            for (int nt = 0; nt < 2; nt++) {
                acc[mt][nt] = __builtin_amdgcn_mfma_f32_16x16x32_bf16(af[mt][0], bfr[nt][0], acc[mt][nt], 0, 0, 0);
                acc[mt][nt] = __builtin_amdgcn_mfma_f32_16x16x32_bf16(af[mt][1], bfr[nt][1], acc[mt][nt], 0, 0, 0);
            }
    }

    #pragma unroll
    for (int nt = 0; nt < 2; nt++) {
        int o = obase + cw + nt * 16 + l15;
        float bb = bias[o];
        #pragma unroll
        for (int mt = 0; mt < 4; mt++) {
            int nrow = nbase + rw + mt * 16 + quad * 4;
            out[(size_t)(nrow + 0) * DIM + o] = acc[mt][nt].x + bb;
            out[(size_t)(nrow + 1) * DIM + o] = acc[mt][nt].y + bb;
            out[(size_t)(nrow + 2) * DIM + o] = acc[mt][nt].z + bb;
            out[(size_t)(nrow + 3) * DIM + o] = acc[mt][nt].w + bb;
        }
    }
}

// ---------------------------------------------------------------------------
extern "C" void kernel_launch(void* const* d_in, const int* in_sizes, int n_in,
                              void* d_out, int out_size, void* d_ws, size_t ws_size,
                              hipStream_t stream)
{
    const float* q        = (const float*)d_in[0];
    const float* k        = (const float*)d_in[1];
    const float* v        = (const float*)d_in[2];
    const float* qk_scale = (const float*)d_in[3];
    const float* w_out    = (const float*)d_in[4];
    const float* b_out    = (const float*)d_in[5];
    float* out = (float*)d_out;

    const size_t per = (size_t)NH * N_CTX * DH;      // 4.19M elements
    ushort* qb    = (ushort*)d_ws;
    ushort* kb    = qb + per;
    ushort* vtg   = kb + per;
    ushort* attnb = vtg + per;                       // (N, DIM) bf16
    ushort* wb    = attnb + per;                     // (DIM, DIM) bf16
    float*  opart = (float*)(wb + (size_t)DIM * DIM);        // 2 x (N, DIM) fp32
    float*  lpart = opart + (size_t)NSPLIT * N_CTX * DIM;    // 2 x NH x N fp32

    prep_kernel<<<dim3(N_CTX * NH / 4), 256, 0, stream>>>(q, qk_scale, qb);
    prep_kernel<<<dim3(N_CTX * NH / 4), 256, 0, stream>>>(k, qk_scale, kb);
    vtrans_kernel<<<dim3(N_CTX / 64, NH), 256, 0, stream>>>(v, vtg);
    wconv_kernel<<<dim3(DIM * DIM / 1024), 256, 0, stream>>>(w_out, wb);
    attn_kernel<<<dim3(N_CTX / 128, NH, NSPLIT), 512, 0, stream>>>(qb, kb, vtg, opart, lpart);
    combine_kernel<<<dim3(N_CTX * DIM / 4 / 256), 256, 0, stream>>>(opart, lpart, attnb);
    proj_kernel<<<dim3(N_CTX / 128, DIM / 64), 256, 0, stream>>>(attnb, wb, b_out, out);
}

// Round 8
// 262.276 us; speedup vs baseline: 6.0235x; 1.0465x over previous
//
#include <hip/hip_runtime.h>
#include <hip/hip_bf16.h>

#define N_CTX 4096
#define NH    16
#define DH    64
#define DIM   1024   // NH * DH
#define NSPLIT 2
#define KT_PER_SPLIT (N_CTX / 64 / NSPLIT)   // 32

typedef __attribute__((ext_vector_type(8))) short bf16x8;  // 8 bf16 in 4 VGPRs
typedef __attribute__((ext_vector_type(4))) float f32x4;   // MFMA C/D

// RNE float->bf16 (non-hot paths)
__device__ __forceinline__ ushort f2bf(float f) {
    union { float f; unsigned u; } x; x.f = f;
    unsigned r = (x.u + 0x7FFFu + ((x.u >> 16) & 1u)) >> 16;
    return (ushort)r;
}
__device__ __forceinline__ unsigned fbits(float f) {
    union { float f; unsigned u; } x; x.f = f; return x.u;
}
// pack two floats to packed bf16 pair (round-half-up), 3 VALU ops
__device__ __forceinline__ unsigned pack_bf16(float lo, float hi) {
    unsigned a = fbits(lo) + 0x8000u;
    unsigned b = fbits(hi) + 0x8000u;
#if defined(__has_builtin)
#if __has_builtin(__builtin_amdgcn_perm)
    return __builtin_amdgcn_perm(b, a, 0x07060302u);
#else
    return (a >> 16) | (b & 0xFFFF0000u);
#endif
#else
    return (a >> 16) | (b & 0xFFFF0000u);
#endif
}
__device__ __forceinline__ float fast_exp2(float x) {
#if defined(__has_builtin)
#if __has_builtin(__builtin_amdgcn_exp2f)
    return __builtin_amdgcn_exp2f(x);
#else
    return exp2f(x);
#endif
#else
    return exp2f(x);
#endif
}

// 0.125 * log2(e): folded into Q during prep; softmax shift-invariance lets us
// drop the bias term entirely (p = exp2(s_mfma) directly, p <= 2^18).
#define SC 0.18033688011112042f

// ---------------------------------------------------------------------------
// prep: x (N, DIM) fp32 -> rope -> l2norm -> * qk_scale -> * premul
//       -> xb bf16 [h][n][d]
// ---------------------------------------------------------------------------
__global__ __launch_bounds__(256) void prep_kernel(
    const float* __restrict__ x, const float* __restrict__ qk_scale,
    ushort* __restrict__ xb, float premul)
{
    const int lane = threadIdx.x & 63;
    const int wave = threadIdx.x >> 6;
    const int row  = blockIdx.x * 4 + wave;   // row = n*NH + h
    const int n = row >> 4;
    const int h = row & 15;

    float val = x[(size_t)n * DIM + h * DH + lane];
    float other = __shfl_xor(val, 1, 64);

    const int i = lane >> 1;
    float inv_freq = 1.0f / powf(10000.0f, (float)i * (1.0f / 32.0f));
    float ang = (float)n * inv_freq;
    float s, c;
    sincosf(ang, &s, &c);

    float r = (lane & 1) ? fmaf(other, s, val * c)
                         : fmaf(val, c, -(other * s));

    float ss = r * r;
    #pragma unroll
    for (int off = 32; off > 0; off >>= 1)
        ss += __shfl_xor(ss, off, 64);
    float invn = 1.0f / fmaxf(sqrtf(ss), 1e-12f);
    float scl  = qk_scale[lane] * premul;

    xb[((size_t)h * N_CTX + n) * DH + lane] = f2bf(r * invn * scl);
}

// ---------------------------------------------------------------------------
// vtrans: v (N, DIM) fp32 -> vt bf16 [h][d][n]
// ---------------------------------------------------------------------------
__global__ __launch_bounds__(256) void vtrans_kernel(
    const float* __restrict__ v, ushort* __restrict__ vt)
{
    __shared__ ushort L[64][68];
    const int kt = blockIdx.x, h = blockIdx.y, t = threadIdx.x;

    for (int e = t; e < 4096; e += 256) {
        int key = e >> 6, d = e & 63;
        float f = v[(size_t)(kt * 64 + key) * DIM + h * DH + d];
        L[d][key] = f2bf(f);
    }
    __syncthreads();
    for (int e = t; e < 4096; e += 256) {
        int d = e >> 6, key = e & 63;
        vt[((size_t)h * DH + d) * N_CTX + kt * 64 + key] = L[d][key];
    }
}

// ---------------------------------------------------------------------------
// wconv: w_out (DIM, DIM) fp32 -> bf16 row-major
// ---------------------------------------------------------------------------
__global__ __launch_bounds__(256) void wconv_kernel(
    const float* __restrict__ w, ushort* __restrict__ wb)
{
    int i = (blockIdx.x * 256 + threadIdx.x) * 4;
    float4 f = *(const float4*)&w[i];
    ushort4 u;
    u.x = f2bf(f.x); u.y = f2bf(f.y); u.z = f2bf(f.z); u.w = f2bf(f.w);
    *(ushort4*)&wb[i] = u;
}

// ---------------------------------------------------------------------------
// attn: MFMA flash attention, fixed-max softmax folded into Q scaling.
// Block: 128 queries x head x split, 256 threads (4 waves).
// Wave w owns queries w*32..+32 end-to-end; K/V frags reused across the
// wave's 2 query-tiles (20 ds_read_b128 : 32 MFMA per wave-ktile).
// 2 barriers/ktile; staging via register prefetch issued post-barrier.
// ---------------------------------------------------------------------------
__global__ __launch_bounds__(256) void attn_kernel(
    const ushort* __restrict__ qb, const ushort* __restrict__ kb,
    const ushort* __restrict__ vt, float* __restrict__ opart,
    float* __restrict__ lpart)
{
    __shared__ ushort Ks[64][72];    // [key][d]
    __shared__ ushort Vt[64][72];    // [d][key]
    __shared__ ushort Ps[128][72];   // [query][key]

    const int h     = blockIdx.y;
    const int qbase = blockIdx.x * 128;
    const int sp    = blockIdx.z;
    const int kbase = sp * (N_CTX / NSPLIT);
    const int t    = threadIdx.x;
    const int w    = t >> 6;
    const int lane = t & 63;
    const int l15  = lane & 15;
    const int quad = lane >> 4;

    // Q B-fragments: 2 query-tiles x 2 k-halves (queries w*32 + qt*16 + l15)
    bf16x8 qf[2][2];
    #pragma unroll
    for (int qt = 0; qt < 2; qt++) {
        const size_t qrow = ((size_t)h * N_CTX + qbase + w * 32 + qt * 16 + l15) * DH;
        qf[qt][0] = *(const bf16x8*)&qb[qrow + quad * 8];
        qf[qt][1] = *(const bf16x8*)&qb[qrow + 32 + quad * 8];
    }

    float l_part[2] = {0.0f, 0.0f};
    f32x4 o_acc[4][2];
    #pragma unroll
    for (int dt = 0; dt < 4; dt++)
        #pragma unroll
        for (int qt = 0; qt < 2; qt++)
            o_acc[dt][qt] = (f32x4){0.f, 0.f, 0.f, 0.f};

    // staging: 256 threads, 2 x 16B chunks each of K and V (rows sr, sr+32)
    const int sr = t >> 3;
    const int sc = (t & 7) * 8;
    const ushort* kp0 = &kb[((size_t)h * N_CTX + kbase + sr) * DH + sc];
    const ushort* kp1 = kp0 + (size_t)32 * DH;
    const ushort* vp0 = &vt[((size_t)h * DH + sr) * N_CTX + kbase + sc];
    const ushort* vp1 = vp0 + (size_t)32 * N_CTX;
    bf16x8 kr0 = *(const bf16x8*)kp0, kr1 = *(const bf16x8*)kp1;
    bf16x8 vr0 = *(const bf16x8*)vp0, vr1 = *(const bf16x8*)vp1;

    for (int kt = 0; kt < KT_PER_SPLIT; kt++) {
        __syncthreads();                       // A: all waves done with prev tile
        *(bf16x8*)&Ks[sr][sc]      = kr0;
        *(bf16x8*)&Ks[sr + 32][sc] = kr1;
        *(bf16x8*)&Vt[sr][sc]      = vr0;
        *(bf16x8*)&Vt[sr + 32][sc] = vr1;
        __syncthreads();                       // B: staging visible
        if (kt + 1 < KT_PER_SPLIT) {           // prefetch next tile into regs
            kr0 = *(const bf16x8*)(kp0 + (size_t)(kt + 1) * 64 * DH);
            kr1 = *(const bf16x8*)(kp1 + (size_t)(kt + 1) * 64 * DH);
            vr0 = *(const bf16x8*)(vp0 + (size_t)(kt + 1) * 64);
            vr1 = *(const bf16x8*)(vp1 + (size_t)(kt + 1) * 64);
        }

        // ---- S phase: 4 key-subtiles; kf frags shared across 2 query-tiles
        #pragma unroll
        for (int j = 0; j < 4; j++) {
            bf16x8 kf0 = *(const bf16x8*)&Ks[j * 16 + l15][quad * 8];
            bf16x8 kf1 = *(const bf16x8*)&Ks[j * 16 + l15][32 + quad * 8];
            f32x4 s0 = (f32x4){0.f, 0.f, 0.f, 0.f};
            f32x4 s1 = (f32x4){0.f, 0.f, 0.f, 0.f};
            s0 = __builtin_amdgcn_mfma_f32_16x16x32_bf16(kf0, qf[0][0], s0, 0, 0, 0);
            s1 = __builtin_amdgcn_mfma_f32_16x16x32_bf16(kf0, qf[1][0], s1, 0, 0, 0);
            s0 = __builtin_amdgcn_mfma_f32_16x16x32_bf16(kf1, qf[0][1], s0, 0, 0, 0);
            s1 = __builtin_amdgcn_mfma_f32_16x16x32_bf16(kf1, qf[1][1], s1, 0, 0, 0);

            // p = exp2(s) (scale pre-folded into Q; bias dropped by shift-inv.)
            {
                float p0 = fast_exp2(s0.x), p1 = fast_exp2(s0.y);
                float p2 = fast_exp2(s0.z), p3 = fast_exp2(s0.w);
                l_part[0] += (p0 + p1) + (p2 + p3);
                uint2 pk; pk.x = pack_bf16(p0, p1); pk.y = pack_bf16(p2, p3);
                *(uint2*)&Ps[w * 32 + l15][j * 16 + quad * 4] = pk;
            }
            {
                float p0 = fast_exp2(s1.x), p1 = fast_exp2(s1.y);
                float p2 = fast_exp2(s1.z), p3 = fast_exp2(s1.w);
                l_part[1] += (p0 + p1) + (p2 + p3);
                uint2 pk; pk.x = pack_bf16(p0, p1); pk.y = pack_bf16(p2, p3);
                *(uint2*)&Ps[w * 32 + 16 + l15][j * 16 + quad * 4] = pk;
            }
        }

        // ---- PV phase: vf frags shared across the wave's 2 query-tiles
        #pragma unroll
        for (int ks = 0; ks < 2; ks++) {
            bf16x8 pf0 = *(const bf16x8*)&Ps[w * 32 + l15][ks * 32 + quad * 8];
            bf16x8 pf1 = *(const bf16x8*)&Ps[w * 32 + 16 + l15][ks * 32 + quad * 8];
            #pragma unroll
            for (int dt = 0; dt < 4; dt++) {
                bf16x8 vf = *(const bf16x8*)&Vt[dt * 16 + l15][ks * 32 + quad * 8];
                o_acc[dt][0] = __builtin_amdgcn_mfma_f32_16x16x32_bf16(vf, pf0, o_acc[dt][0], 0, 0, 0);
                o_acc[dt][1] = __builtin_amdgcn_mfma_f32_16x16x32_bf16(vf, pf1, o_acc[dt][1], 0, 0, 0);
            }
        }
    }

    // l: reduce across quads (disjoint key subsets per quad)
    #pragma unroll
    for (int qt = 0; qt < 2; qt++) {
        float v = l_part[qt];
        v += __shfl_xor(v, 16, 64);
        v += __shfl_xor(v, 32, 64);
        if (quad == 0)
            lpart[(size_t)sp * NH * N_CTX + (size_t)h * N_CTX
                  + qbase + w * 32 + qt * 16 + l15] = v;
    }

    // O partial (pre-division), fp32 (N, DIM) layout per split
    #pragma unroll
    for (int qt = 0; qt < 2; qt++)
        #pragma unroll
        for (int dt = 0; dt < 4; dt++) {
            f32x4 o = o_acc[dt][qt];
            float4 ov; ov.x = o.x; ov.y = o.y; ov.z = o.z; ov.w = o.w;
            *(float4*)&opart[((size_t)sp * N_CTX + qbase + w * 32 + qt * 16 + l15) * DIM
                             + h * DH + dt * 16 + quad * 4] = ov;
        }
}

// ---------------------------------------------------------------------------
// combine: attnb[n][c] = bf16( (O0+O1)[n][c] / (l0+l1)[n,h] )
// ---------------------------------------------------------------------------
__global__ __launch_bounds__(256) void combine_kernel(
    const float* __restrict__ opart, const float* __restrict__ lpart,
    ushort* __restrict__ attnb)
{
    const int idx = blockIdx.x * 256 + threadIdx.x;   // one per 4 elements
    const int n   = idx >> 8;
    const int rem = idx & 255;
    const int h   = rem >> 4;
    const size_t e = (size_t)n * DIM + h * DH + (rem & 15) * 4;

    float4 o0 = *(const float4*)&opart[e];
    float4 o1 = *(const float4*)&opart[(size_t)N_CTX * DIM + e];
    float l0 = lpart[(size_t)h * N_CTX + n];
    float l1 = lpart[(size_t)NH * N_CTX + (size_t)h * N_CTX + n];
    float li = 1.0f / (l0 + l1);

    ushort4 r;
    r.x = f2bf((o0.x + o1.x) * li);
    r.y = f2bf((o0.y + o1.y) * li);
    r.z = f2bf((o0.z + o1.z) * li);
    r.w = f2bf((o0.w + o1.w) * li);
    *(ushort4*)&attnb[e] = r;
}

// ---------------------------------------------------------------------------
// proj (MFMA): out[n][o] = sum_c A[n][c] * W[o][c] + b[o]   (unchanged)
// ---------------------------------------------------------------------------
__global__ __launch_bounds__(256) void proj_kernel(
    const ushort* __restrict__ A, const ushort* __restrict__ W,
    const float* __restrict__ bias, float* __restrict__ out)
{
    __shared__ ushort As[128][72];
    __shared__ ushort Ws[64][72];

    const int nbase = blockIdx.x * 128;
    const int obase = blockIdx.y * 64;
    const int t    = threadIdx.x;
    const int w    = t >> 6;
    const int lane = t & 63;
    const int l15  = lane & 15;
    const int quad = lane >> 4;
    const int rw   = (w >> 1) * 64;
    const int cw   = (w & 1) * 32;

    f32x4 acc[4][2];
    #pragma unroll
    for (int mt = 0; mt < 4; mt++)
        #pragma unroll
        for (int nt = 0; nt < 2; nt++)
            acc[mt][nt] = (f32x4){0.f, 0.f, 0.f, 0.f};

    for (int kt = 0; kt < DIM / 64; kt++) {
        const int kb = kt * 64;
        __syncthreads();
        #pragma unroll
        for (int i = 0; i < 4; i++) {
            int c = t + i * 256, r = c >> 3, c8 = c & 7;
            *(bf16x8*)&As[r][c8 * 8] =
                *(const bf16x8*)&A[(size_t)(nbase + r) * DIM + kb + c8 * 8];
        }
        #pragma unroll
        for (int i = 0; i < 2; i++) {
            int c = t + i * 256, r = c >> 3, c8 = c & 7;
            *(bf16x8*)&Ws[r][c8 * 8] =
                *(const bf16x8*)&W[(size_t)(obase + r) * DIM + kb + c8 * 8];
        }
        __syncthreads();

        bf16x8 af[4][2], bfr[2][2];
        #pragma unroll
        for (int mt = 0; mt < 4; mt++)
            #pragma unroll
            for (int kh = 0; kh < 2; kh++)
                af[mt][kh] = *(const bf16x8*)&As[rw + mt * 16 + l15][kh * 32 + quad * 8];
        #pragma unroll
        for (int nt = 0; nt < 2; nt++)
            #pragma unroll
            for (int kh = 0; kh < 2; kh++)
                bfr[nt][kh] = *(const bf16x8*)&Ws[cw + nt * 16 + l15][kh * 32 + quad * 8];

        #pragma unroll
        for (int mt = 0; mt < 4; mt++)
            #pragma unroll
            for (int nt = 0; nt < 2; nt++) {
                acc[mt][nt] = __builtin_amdgcn_mfma_f32_16x16x32_bf16(af[mt][0], bfr[nt][0], acc[mt][nt], 0, 0, 0);
                acc[mt][nt] = __builtin_amdgcn_mfma_f32_16x16x32_bf16(af[mt][1], bfr[nt][1], acc[mt][nt], 0, 0, 0);
            }
    }

    #pragma unroll
    for (int nt = 0; nt < 2; nt++) {
        int o = obase + cw + nt * 16 + l15;
        float bb = bias[o];
        #pragma unroll
        for (int mt = 0; mt < 4; mt++) {
            int nrow = nbase + rw + mt * 16 + quad * 4;
            out[(size_t)(nrow + 0) * DIM + o] = acc[mt][nt].x + bb;
            out[(size_t)(nrow + 1) * DIM + o] = acc[mt][nt].y + bb;
            out[(size_t)(nrow + 2) * DIM + o] = acc[mt][nt].z + bb;
            out[(size_t)(nrow + 3) * DIM + o] = acc[mt][nt].w + bb;
        }
    }
}

// ---------------------------------------------------------------------------
extern "C" void kernel_launch(void* const* d_in, const int* in_sizes, int n_in,
                              void* d_out, int out_size, void* d_ws, size_t ws_size,
                              hipStream_t stream)
{
    const float* q        = (const float*)d_in[0];
    const float* k        = (const float*)d_in[1];
    const float* v        = (const float*)d_in[2];
    const float* qk_scale = (const float*)d_in[3];
    const float* w_out    = (const float*)d_in[4];
    const float* b_out    = (const float*)d_in[5];
    float* out = (float*)d_out;

    const size_t per = (size_t)NH * N_CTX * DH;      // 4.19M elements
    ushort* qb    = (ushort*)d_ws;
    ushort* kb    = qb + per;
    ushort* vtg   = kb + per;
    ushort* attnb = vtg + per;                       // (N, DIM) bf16
    ushort* wb    = attnb + per;                     // (DIM, DIM) bf16
    float*  opart = (float*)(wb + (size_t)DIM * DIM);        // 2 x (N, DIM) fp32
    float*  lpart = opart + (size_t)NSPLIT * N_CTX * DIM;    // 2 x NH x N fp32

    prep_kernel<<<dim3(N_CTX * NH / 4), 256, 0, stream>>>(q, qk_scale, qb, SC);
    prep_kernel<<<dim3(N_CTX * NH / 4), 256, 0, stream>>>(k, qk_scale, kb, 1.0f);
    vtrans_kernel<<<dim3(N_CTX / 64, NH), 256, 0, stream>>>(v, vtg);
    wconv_kernel<<<dim3(DIM * DIM / 1024), 256, 0, stream>>>(w_out, wb);
    attn_kernel<<<dim3(N_CTX / 128, NH, NSPLIT), 256, 0, stream>>>(qb, kb, vtg, opart, lpart);
    combine_kernel<<<dim3(N_CTX * DIM / 4 / 256), 256, 0, stream>>>(opart, lpart, attnb);
    proj_kernel<<<dim3(N_CTX / 128, DIM / 64), 256, 0, stream>>>(attnb, wb, b_out, out);
}